// Round 2
// baseline (2255.923 us; speedup 1.0000x reference)
//
#include <hip/hip_runtime.h>
#include <hip/hip_bf16.h>

// Shapes: B=4096, x(4,64,64); conv1 32x4x8x8 s4 -> (32,15,15); conv2 64x32x4x4 s2 -> (64,6,6);
// conv3 64x64x3x3 s1 -> (64,4,4) -> h(1024); routed MLPs E=4: 1024->512->{32,1}; q=(B,32) f32.

// ---------------- fused conv1+conv2: one block per image ----------------
__global__ __launch_bounds__(288) void k_conv12(const float* __restrict__ x,
    const float* __restrict__ W1, const float* __restrict__ b1,
    const float* __restrict__ W2, const float* __restrict__ b2,
    float* __restrict__ h2) {
  __shared__ float sx[16384];   // 4x64x64 input image (64 KB)
  __shared__ float sh[7200];    // 32x15x15 conv1 output (28.8 KB)
  const int b = blockIdx.x, tid = threadIdx.x;

  // stage input image
  const float4* xs = (const float4*)(x + (size_t)b * 16384);
  float4* s4 = (float4*)sx;
  for (int i = tid; i < 4096; i += 288) s4[i] = xs[i];
  __syncthreads();

  // conv1: thread = output position (225 active), acc over all 32 oc, weights wave-uniform
  if (tid < 225) {
    const int oy = tid / 15, ox = tid % 15;
    float acc[32];
    #pragma unroll
    for (int oc = 0; oc < 32; ++oc) acc[oc] = b1[oc];
    for (int ic = 0; ic < 4; ++ic) {
      for (int ky = 0; ky < 8; ++ky) {
        const float* xr = &sx[ic * 4096 + (oy * 4 + ky) * 64 + ox * 4];
        float xv[8];
        #pragma unroll
        for (int kx = 0; kx < 8; ++kx) xv[kx] = xr[kx];
        const float* wr = W1 + ic * 64 + ky * 8;   // uniform across lanes -> scalar loads
        #pragma unroll
        for (int oc = 0; oc < 32; ++oc) {
          const float* w8 = wr + oc * 256;
          float a = acc[oc];
          #pragma unroll
          for (int kx = 0; kx < 8; ++kx) a = fmaf(xv[kx], w8[kx], a);
          acc[oc] = a;
        }
      }
    }
    #pragma unroll
    for (int oc = 0; oc < 32; ++oc) sh[oc * 225 + tid] = fmaxf(acc[oc], 0.f);
  }
  __syncthreads();

  // conv2: 288 threads = 36 positions x 8 oc-groups (8 oc each), exact 2304 outputs
  const int p = tid % 36, g = tid / 36;        // g in 0..7
  const int oy = p / 6, ox = p % 6;
  float acc2[8];
  #pragma unroll
  for (int r = 0; r < 8; ++r) acc2[r] = b2[g * 8 + r];
  for (int ic = 0; ic < 32; ++ic) {
    #pragma unroll
    for (int ky = 0; ky < 4; ++ky) {
      const float* xr = &sh[ic * 225 + (oy * 2 + ky) * 15 + ox * 2];
      const float x0 = xr[0], x1 = xr[1], x2 = xr[2], x3 = xr[3];
      const float* wbase = W2 + (size_t)(g * 8) * 512 + ic * 16 + ky * 4;
      #pragma unroll
      for (int r = 0; r < 8; ++r) {
        const float4 w = *(const float4*)(wbase + r * 512);
        acc2[r] = fmaf(x0, w.x, fmaf(x1, w.y, fmaf(x2, w.z, fmaf(x3, w.w, acc2[r]))));
      }
    }
  }
  float* dst = h2 + (size_t)b * 2304 + p;
  #pragma unroll
  for (int r = 0; r < 8; ++r) dst[(g * 8 + r) * 36] = fmaxf(acc2[r], 0.f);
}

// ---------------- conv3: 4 images per block ----------------
__global__ __launch_bounds__(256) void k_conv3(const float* __restrict__ h2,
    const float* __restrict__ W, const float* __restrict__ bias,
    float* __restrict__ h3) {
  __shared__ float sx[4][2304];   // 4 images x 64x6x6 (36.9 KB)
  const int tid = threadIdx.x;
  const float4* src = (const float4*)(h2 + (size_t)blockIdx.x * 4 * 2304);
  float4* s4 = (float4*)&sx[0][0];
  #pragma unroll
  for (int i = 0; i < 9; ++i) s4[tid + i * 256] = src[tid + i * 256];
  __syncthreads();
  const int img = tid >> 6, l = tid & 63;
  const int p = l & 15, ocg = l >> 4;          // oc group (4 groups of 16)
  const int oy = p >> 2, ox = p & 3;
  float acc[16];
  #pragma unroll
  for (int j = 0; j < 16; ++j) acc[j] = bias[ocg * 16 + j];
  for (int ic = 0; ic < 64; ++ic) {
    #pragma unroll
    for (int ky = 0; ky < 3; ++ky) {
      const float* xr = &sx[img][ic * 36 + (oy + ky) * 6 + ox];
      const float x0 = xr[0], x1 = xr[1], x2 = xr[2];
      const float* wr = W + (size_t)(ocg * 16) * 576 + ic * 9 + ky * 3;
      #pragma unroll
      for (int j = 0; j < 16; ++j) {
        const float* w = wr + j * 576;
        acc[j] = fmaf(x0, w[0], fmaf(x1, w[1], fmaf(x2, w[2], acc[j])));
      }
    }
  }
  const int b = blockIdx.x * 4 + img;
  float* dst = h3 + (size_t)b * 1024 + (ocg * 16) * 16 + p;
  #pragma unroll
  for (int j = 0; j < 16; ++j) dst[j * 16] = fmaxf(acc[j], 0.f);
}

// ---------------- routing: expert index + bucket per expert ----------------
__global__ void k_route(const float* __restrict__ x, const float* __restrict__ bd,
                        int* __restrict__ perm, int* __restrict__ cnt) {
  const int b = blockIdx.x * 256 + threadIdx.x;
  const float r = x[(size_t)b * 16384 + 12288];   // x[b,3,0,0]
  const int e = (r > bd[0]) + (r > bd[1]) + (r > bd[2]);
  const int pos = atomicAdd(&cnt[e], 1);
  perm[e * 4096 + pos] = b;
}

// ---------------- MLP layer 1: expert-sorted tiled GEMM, M=cnt[e], K=1024, N=512 ----------
// z rows indexed by ORIGINAL batch index (scatter) so experts never collide.
__global__ __launch_bounds__(256) void k_mlp1(const float* __restrict__ h3,
    const float* __restrict__ aW1, const float* __restrict__ ab1,
    const float* __restrict__ vW1, const float* __restrict__ vb1,
    const int* __restrict__ perm, const int* __restrict__ cnt,
    float* __restrict__ za, float* __restrict__ zv) {
  const int e = blockIdx.z & 3, net = blockIdx.z >> 2;
  const int cntE = cnt[e];
  const int m0 = blockIdx.x * 64;
  if (m0 >= cntE) return;
  const int n0 = blockIdx.y * 64;
  const float* W = (net ? vW1 : aW1) + (size_t)e * (1024 * 512);
  const float* bb = (net ? vb1 : ab1) + e * 512;
  float* z = net ? zv : za;

  __shared__ float Ast[64][68];   // transposed A tile [k][row]
  __shared__ float Bs[64][64];
  __shared__ int rows[64];
  const int tid = threadIdx.x;
  if (tid < 64) {
    const int j = m0 + tid;
    rows[tid] = perm[e * 4096 + (j < cntE ? j : cntE - 1)];
  }
  __syncthreads();

  const int tx = tid & 15, ty = tid >> 4;
  const int r = tid >> 2, q = (tid & 3) * 16;
  float acc[4][4] = {};
  for (int k0 = 0; k0 < 1024; k0 += 64) {
    const float4* ap = (const float4*)(h3 + (size_t)rows[r] * 1024 + k0 + q);
    #pragma unroll
    for (int u = 0; u < 4; ++u) {
      const float4 v = ap[u];
      Ast[q + u * 4 + 0][r] = v.x;
      Ast[q + u * 4 + 1][r] = v.y;
      Ast[q + u * 4 + 2][r] = v.z;
      Ast[q + u * 4 + 3][r] = v.w;
    }
    const float4* bp = (const float4*)(W + (size_t)(k0 + r) * 512 + n0 + q);
    float4* bd4 = (float4*)&Bs[r][q];
    #pragma unroll
    for (int u = 0; u < 4; ++u) bd4[u] = bp[u];
    __syncthreads();
    #pragma unroll
    for (int kk = 0; kk < 64; ++kk) {
      const float4 av = *(const float4*)&Ast[kk][ty * 4];
      const float4 bv = *(const float4*)&Bs[kk][tx * 4];
      acc[0][0] = fmaf(av.x, bv.x, acc[0][0]); acc[0][1] = fmaf(av.x, bv.y, acc[0][1]);
      acc[0][2] = fmaf(av.x, bv.z, acc[0][2]); acc[0][3] = fmaf(av.x, bv.w, acc[0][3]);
      acc[1][0] = fmaf(av.y, bv.x, acc[1][0]); acc[1][1] = fmaf(av.y, bv.y, acc[1][1]);
      acc[1][2] = fmaf(av.y, bv.z, acc[1][2]); acc[1][3] = fmaf(av.y, bv.w, acc[1][3]);
      acc[2][0] = fmaf(av.z, bv.x, acc[2][0]); acc[2][1] = fmaf(av.z, bv.y, acc[2][1]);
      acc[2][2] = fmaf(av.z, bv.z, acc[2][2]); acc[2][3] = fmaf(av.z, bv.w, acc[2][3]);
      acc[3][0] = fmaf(av.w, bv.x, acc[3][0]); acc[3][1] = fmaf(av.w, bv.y, acc[3][1]);
      acc[3][2] = fmaf(av.w, bv.z, acc[3][2]); acc[3][3] = fmaf(av.w, bv.w, acc[3][3]);
    }
    __syncthreads();
  }
  #pragma unroll
  for (int i = 0; i < 4; ++i) {
    const int j = m0 + ty * 4 + i;
    if (j < cntE) {
      float* zr = z + (size_t)rows[ty * 4 + i] * 512 + n0 + tx * 4;
      #pragma unroll
      for (int u = 0; u < 4; ++u)
        zr[u] = fmaxf(acc[i][u] + bb[n0 + tx * 4 + u], 0.f);
    }
  }
}

// ---------------- MLP layer 2 + dueling combine, weights in LDS ----------------
__global__ __launch_bounds__(256) void k_mlp2(const float* __restrict__ za,
    const float* __restrict__ zv,
    const float* __restrict__ aW2, const float* __restrict__ ab2,
    const float* __restrict__ vW2, const float* __restrict__ vb2,
    const int* __restrict__ perm, const int* __restrict__ cnt,
    float* __restrict__ out) {
  __shared__ float wa[512 * 32];  // 64 KB
  __shared__ float wv[512];
  const int e = blockIdx.y;
  const int tid = threadIdx.x;
  {
    const float4* s = (const float4*)(aW2 + (size_t)e * 16384);
    float4* d = (float4*)wa;
    #pragma unroll
    for (int i = 0; i < 16; ++i) d[tid + i * 256] = s[tid + i * 256];
    if (tid < 128) ((float4*)wv)[tid] = ((const float4*)(vW2 + (size_t)e * 512))[tid];
  }
  __syncthreads();
  const int cntE = cnt[e];
  const int j = blockIdx.x * 256 + tid;
  if (j >= cntE) return;
  const int b = perm[e * 4096 + j];

  float acca[32];
  #pragma unroll
  for (int a = 0; a < 32; ++a) acca[a] = ab2[e * 32 + a];
  float accv = vb2[e];
  const float4* zar = (const float4*)(za + (size_t)b * 512);
  const float4* zvr = (const float4*)(zv + (size_t)b * 512);
  for (int k4 = 0; k4 < 128; ++k4) {
    const float4 z1 = zar[k4];
    const float4 z2 = zvr[k4];
    const float* wvk = &wv[k4 * 4];
    accv = fmaf(z2.x, wvk[0], accv);
    accv = fmaf(z2.y, wvk[1], accv);
    accv = fmaf(z2.z, wvk[2], accv);
    accv = fmaf(z2.w, wvk[3], accv);
    const float* w = &wa[k4 * 4 * 32];
    #pragma unroll
    for (int a = 0; a < 32; ++a) acca[a] = fmaf(z1.x, w[a], acca[a]);
    #pragma unroll
    for (int a = 0; a < 32; ++a) acca[a] = fmaf(z1.y, w[32 + a], acca[a]);
    #pragma unroll
    for (int a = 0; a < 32; ++a) acca[a] = fmaf(z1.z, w[64 + a], acca[a]);
    #pragma unroll
    for (int a = 0; a < 32; ++a) acca[a] = fmaf(z1.w, w[96 + a], acca[a]);
  }
  float mean = 0.f;
  #pragma unroll
  for (int a = 0; a < 32; ++a) mean += acca[a];
  mean *= 0.03125f;
  float* o = out + (size_t)b * 32;
  #pragma unroll
  for (int a = 0; a < 32; ++a) o[a] = acca[a] - mean + accv;
}

extern "C" void kernel_launch(void* const* d_in, const int* in_sizes, int n_in,
                              void* d_out, int out_size, void* d_ws, size_t ws_size,
                              hipStream_t stream) {
  const float* x   = (const float*)d_in[0];
  const float* cW1 = (const float*)d_in[1];
  const float* cb1 = (const float*)d_in[2];
  const float* cW2 = (const float*)d_in[3];
  const float* cb2 = (const float*)d_in[4];
  const float* cW3 = (const float*)d_in[5];
  const float* cb3 = (const float*)d_in[6];
  const float* aW1 = (const float*)d_in[7];
  const float* ab1 = (const float*)d_in[8];
  const float* aW2 = (const float*)d_in[9];
  const float* ab2 = (const float*)d_in[10];
  const float* vW1 = (const float*)d_in[11];
  const float* vb1 = (const float*)d_in[12];
  const float* vW2 = (const float*)d_in[13];
  const float* vb2 = (const float*)d_in[14];
  const float* bd  = (const float*)d_in[15];
  float* out = (float*)d_out;

  char* ws = (char*)d_ws;
  float* h2 = (float*)(ws);                         // 4096*2304*4 = 37,748,736
  float* h3 = (float*)(ws + 37748736ull);           // 16,777,216
  float* za = (float*)(ws + 54525952ull);           // 4096*512*4 = 8,388,608 (by batch idx)
  float* zv = (float*)(ws + 62914560ull);           // 8,388,608 (by batch idx)
  int* perm = (int*)(ws + 71303168ull);             // 65,536
  int* cnt  = (int*)(ws + 71368704ull);             // 16

  hipMemsetAsync(cnt, 0, 16, stream);
  k_route<<<16, 256, 0, stream>>>(x, bd, perm, cnt);
  k_conv12<<<4096, 288, 0, stream>>>(x, cW1, cb1, cW2, cb2, h2);
  k_conv3<<<1024, 256, 0, stream>>>(h2, cW3, cb3, h3);
  k_mlp1<<<dim3(64, 8, 8), 256, 0, stream>>>(h3, aW1, ab1, vW1, vb1, perm, cnt, za, zv);
  k_mlp2<<<dim3(16, 4), 256, 0, stream>>>(za, zv, aW2, ab2, vW2, vb2, perm, cnt, out);
}

// Round 3
// 592.262 us; speedup vs baseline: 3.8090x; 3.8090x over previous
//
#include <hip/hip_runtime.h>
#include <hip/hip_bf16.h>

typedef __bf16 bf16;
typedef bf16 bf16x8 __attribute__((ext_vector_type(8)));
typedef float f32x4 __attribute__((ext_vector_type(4)));

// Shapes: B=4096, x(4,64,64); conv1 32x4x8x8 s4 -> (32,15,15); conv2 64x32x4x4 s2 -> (64,6,6);
// conv3 64x64x3x3 s1 -> (64,4,4) -> h(1024); routed MLPs E=4: 1024->512->{32,1}; q=(B,32) f32.
//
// Convs as bf16 MFMA GEMMs with K reordered as (ky,kx,ic) so A-fragments are contiguous
// b128 LDS reads from channel-last activations, B-fragments are contiguous 16B global
// loads from pre-permuted bf16 weights [oc][ky][kx][ic].

// ---- weight convert+permute: OIHW f32 -> [oc][ky][kx][ic] bf16 ----
__global__ void k_cvt_w1(const float* __restrict__ w, bf16* __restrict__ o) {
  int i = blockIdx.x * 256 + threadIdx.x;
  if (i >= 32 * 256) return;
  int oc = i >> 8, k = i & 255;
  int ic = k & 3, kp = k >> 2, kx = kp & 7, ky = kp >> 3;
  o[i] = (bf16)w[oc * 256 + ic * 64 + ky * 8 + kx];
}
__global__ void k_cvt_w2(const float* __restrict__ w, bf16* __restrict__ o) {
  int i = blockIdx.x * 256 + threadIdx.x;
  if (i >= 64 * 512) return;
  int oc = i >> 9, k = i & 511;
  int ic = k & 31, kp = k >> 5, kx = kp & 3, ky = kp >> 2;
  o[i] = (bf16)w[oc * 512 + ic * 16 + ky * 4 + kx];
}
__global__ void k_cvt_w3(const float* __restrict__ w, bf16* __restrict__ o) {
  int i = blockIdx.x * 256 + threadIdx.x;
  if (i >= 64 * 576) return;
  int oc = i / 576, k = i - oc * 576;
  int ic = k & 63, kp = k >> 6, kx = kp % 3, ky = kp / 3;
  o[i] = (bf16)w[oc * 576 + ic * 9 + ky * 3 + kx];
}

// ---- fused conv1+conv2+conv3, one block per image, bf16 MFMA ----
__global__ __launch_bounds__(256) void k_convs(const float* __restrict__ x,
    const bf16* __restrict__ W1p, const float* __restrict__ b1,
    const bf16* __restrict__ W2p, const float* __restrict__ b2,
    const bf16* __restrict__ W3p, const float* __restrict__ b3,
    float* __restrict__ h3) {
  __shared__ bf16 sx[64 * 64 * 4];    // 32 KB  [y][x][ic]
  __shared__ bf16 sh1[15 * 15 * 32];  // 14.4 KB [y][x][oc]
  __shared__ bf16 sh2[6 * 6 * 64];    // 4.6 KB [y][x][oc]
  const int b = blockIdx.x, tid = threadIdx.x;
  const int lane = tid & 63, wave = tid >> 6;
  const int lid = lane & 15, c = lane >> 4;

  // stage x: f32 [4][64][64] -> bf16 channel-last [64][64][4]
  {
    const float4* xs = (const float4*)(x + (size_t)b * 16384);
    for (int i = tid; i < 4096; i += 256) {
      float4 v = xs[i];
      int ic = i >> 10, p0 = (i & 1023) * 4;
      sx[(p0 + 0) * 4 + ic] = (bf16)v.x;
      sx[(p0 + 1) * 4 + ic] = (bf16)v.y;
      sx[(p0 + 2) * 4 + ic] = (bf16)v.z;
      sx[(p0 + 3) * 4 + ic] = (bf16)v.w;
    }
  }
  __syncthreads();

  // conv1: M=225(15 ptiles), N=32(2 octiles), K=256 (k=(ky*8+kx)*4+ic, kstep<->ky)
  for (int t = wave; t < 30; t += 4) {
    const int pt = t >> 1, ot = t & 1;
    const int p = pt * 16 + lid;
    const int py = p / 15, px = p - py * 15;
    const int abase = py * 1024 + px * 16 + c * 8;   // + ks*256
    const int col = ot * 16 + lid;
    const bf16* wb = W1p + col * 256 + c * 8;        // + ks*32
    const float bias = b1[col];
    f32x4 acc = {0.f, 0.f, 0.f, 0.f};
    #pragma unroll
    for (int ks = 0; ks < 8; ++ks) {
      bf16x8 av = *(const bf16x8*)(&sx[abase + ks * 256]);
      bf16x8 bv = *(const bf16x8*)(wb + ks * 32);
      acc = __builtin_amdgcn_mfma_f32_16x16x32_bf16(av, bv, acc, 0, 0, 0);
    }
    #pragma unroll
    for (int r = 0; r < 4; ++r) {
      const int pr = pt * 16 + c * 4 + r;
      if (pr < 225) sh1[pr * 32 + col] = (bf16)fmaxf(acc[r] + bias, 0.f);
    }
  }
  __syncthreads();

  // conv2: M=36(3 ptiles), N=64(4 octiles), K=512 (k=(ky*4+kx)*32+ic, kstep<->(ky,kx))
  for (int t = wave; t < 12; t += 4) {
    const int pt = t >> 2, ot = t & 3;
    const int p = pt * 16 + lid;
    const int oy = p / 6, ox = p - oy * 6;
    const int abase = (oy * 2 * 15 + ox * 2) * 32 + c * 8;
    const int col = ot * 16 + lid;
    const bf16* wb = W2p + col * 512 + c * 8;
    const float bias = b2[col];
    f32x4 acc = {0.f, 0.f, 0.f, 0.f};
    #pragma unroll
    for (int ks = 0; ks < 16; ++ks) {
      const int ky = ks >> 2, kx = ks & 3;
      bf16x8 av = *(const bf16x8*)(&sh1[abase + (ky * 15 + kx) * 32]);
      bf16x8 bv = *(const bf16x8*)(wb + ks * 32);
      acc = __builtin_amdgcn_mfma_f32_16x16x32_bf16(av, bv, acc, 0, 0, 0);
    }
    #pragma unroll
    for (int r = 0; r < 4; ++r) {
      const int pr = pt * 16 + c * 4 + r;
      if (pr < 36) sh2[pr * 64 + col] = (bf16)fmaxf(acc[r] + bias, 0.f);
    }
  }
  __syncthreads();

  // conv3: M=16(1 ptile), N=64(wave=octile), K=576 (k=(ky*3+kx)*64+ic)
  {
    const int p = lid;
    const int oy = p >> 2, ox = p & 3;
    const int abase = (oy * 6 + ox) * 64 + c * 8;
    const int col = wave * 16 + lid;
    const bf16* wb = W3p + col * 576 + c * 8;
    const float bias = b3[col];
    f32x4 acc = {0.f, 0.f, 0.f, 0.f};
    #pragma unroll
    for (int ks = 0; ks < 18; ++ks) {
      const int kp = ks >> 1, ky = kp / 3, kx = kp - ky * 3;
      bf16x8 av = *(const bf16x8*)(&sh2[abase + (ky * 6 + kx) * 64 + (ks & 1) * 32]);
      bf16x8 bv = *(const bf16x8*)(wb + ks * 32);
      acc = __builtin_amdgcn_mfma_f32_16x16x32_bf16(av, bv, acc, 0, 0, 0);
    }
    // h[b][oc*16 + p]: lane writes 4 consecutive p -> one float4
    float4 o;
    o.x = fmaxf(acc[0] + bias, 0.f);
    o.y = fmaxf(acc[1] + bias, 0.f);
    o.z = fmaxf(acc[2] + bias, 0.f);
    o.w = fmaxf(acc[3] + bias, 0.f);
    *(float4*)(h3 + (size_t)b * 1024 + col * 16 + c * 4) = o;
  }
}

// ---------------- routing: expert index + bucket per expert ----------------
__global__ void k_route(const float* __restrict__ x, const float* __restrict__ bd,
                        int* __restrict__ perm, int* __restrict__ cnt) {
  const int b = blockIdx.x * 256 + threadIdx.x;
  const float r = x[(size_t)b * 16384 + 12288];   // x[b,3,0,0]
  const int e = (r > bd[0]) + (r > bd[1]) + (r > bd[2]);
  const int pos = atomicAdd(&cnt[e], 1);
  perm[e * 4096 + pos] = b;
}

// ---------------- MLP layer 1: expert-sorted tiled GEMM (f32) ----------------
__global__ __launch_bounds__(256) void k_mlp1(const float* __restrict__ h3,
    const float* __restrict__ aW1, const float* __restrict__ ab1,
    const float* __restrict__ vW1, const float* __restrict__ vb1,
    const int* __restrict__ perm, const int* __restrict__ cnt,
    float* __restrict__ za, float* __restrict__ zv) {
  const int e = blockIdx.z & 3, net = blockIdx.z >> 2;
  const int cntE = cnt[e];
  const int m0 = blockIdx.x * 64;
  if (m0 >= cntE) return;
  const int n0 = blockIdx.y * 64;
  const float* W = (net ? vW1 : aW1) + (size_t)e * (1024 * 512);
  const float* bb = (net ? vb1 : ab1) + e * 512;
  float* z = net ? zv : za;

  __shared__ float Ast[64][68];
  __shared__ float Bs[64][64];
  __shared__ int rows[64];
  const int tid = threadIdx.x;
  if (tid < 64) {
    const int j = m0 + tid;
    rows[tid] = perm[e * 4096 + (j < cntE ? j : cntE - 1)];
  }
  __syncthreads();

  const int tx = tid & 15, ty = tid >> 4;
  const int r = tid >> 2, q = (tid & 3) * 16;
  float acc[4][4] = {};
  for (int k0 = 0; k0 < 1024; k0 += 64) {
    const float4* ap = (const float4*)(h3 + (size_t)rows[r] * 1024 + k0 + q);
    #pragma unroll
    for (int u = 0; u < 4; ++u) {
      const float4 v = ap[u];
      Ast[q + u * 4 + 0][r] = v.x;
      Ast[q + u * 4 + 1][r] = v.y;
      Ast[q + u * 4 + 2][r] = v.z;
      Ast[q + u * 4 + 3][r] = v.w;
    }
    const float4* bp = (const float4*)(W + (size_t)(k0 + r) * 512 + n0 + q);
    float4* bd4 = (float4*)&Bs[r][q];
    #pragma unroll
    for (int u = 0; u < 4; ++u) bd4[u] = bp[u];
    __syncthreads();
    #pragma unroll
    for (int kk = 0; kk < 64; ++kk) {
      const float4 av = *(const float4*)&Ast[kk][ty * 4];
      const float4 bv = *(const float4*)&Bs[kk][tx * 4];
      acc[0][0] = fmaf(av.x, bv.x, acc[0][0]); acc[0][1] = fmaf(av.x, bv.y, acc[0][1]);
      acc[0][2] = fmaf(av.x, bv.z, acc[0][2]); acc[0][3] = fmaf(av.x, bv.w, acc[0][3]);
      acc[1][0] = fmaf(av.y, bv.x, acc[1][0]); acc[1][1] = fmaf(av.y, bv.y, acc[1][1]);
      acc[1][2] = fmaf(av.y, bv.z, acc[1][2]); acc[1][3] = fmaf(av.y, bv.w, acc[1][3]);
      acc[2][0] = fmaf(av.z, bv.x, acc[2][0]); acc[2][1] = fmaf(av.z, bv.y, acc[2][1]);
      acc[2][2] = fmaf(av.z, bv.z, acc[2][2]); acc[2][3] = fmaf(av.z, bv.w, acc[2][3]);
      acc[3][0] = fmaf(av.w, bv.x, acc[3][0]); acc[3][1] = fmaf(av.w, bv.y, acc[3][1]);
      acc[3][2] = fmaf(av.w, bv.z, acc[3][2]); acc[3][3] = fmaf(av.w, bv.w, acc[3][3]);
    }
    __syncthreads();
  }
  #pragma unroll
  for (int i = 0; i < 4; ++i) {
    const int j = m0 + ty * 4 + i;
    if (j < cntE) {
      float* zr = z + (size_t)rows[ty * 4 + i] * 512 + n0 + tx * 4;
      #pragma unroll
      for (int u = 0; u < 4; ++u)
        zr[u] = fmaxf(acc[i][u] + bb[n0 + tx * 4 + u], 0.f);
    }
  }
}

// ---------------- MLP layer 2 + dueling combine ----------------
__global__ __launch_bounds__(256) void k_mlp2(const float* __restrict__ za,
    const float* __restrict__ zv,
    const float* __restrict__ aW2, const float* __restrict__ ab2,
    const float* __restrict__ vW2, const float* __restrict__ vb2,
    const int* __restrict__ perm, const int* __restrict__ cnt,
    float* __restrict__ out) {
  __shared__ float wa[512 * 32];
  __shared__ float wv[512];
  const int e = blockIdx.y;
  const int tid = threadIdx.x;
  {
    const float4* s = (const float4*)(aW2 + (size_t)e * 16384);
    float4* d = (float4*)wa;
    #pragma unroll
    for (int i = 0; i < 16; ++i) d[tid + i * 256] = s[tid + i * 256];
    if (tid < 128) ((float4*)wv)[tid] = ((const float4*)(vW2 + (size_t)e * 512))[tid];
  }
  __syncthreads();
  const int cntE = cnt[e];
  const int j = blockIdx.x * 256 + tid;
  if (j >= cntE) return;
  const int b = perm[e * 4096 + j];

  float acca[32];
  #pragma unroll
  for (int a = 0; a < 32; ++a) acca[a] = ab2[e * 32 + a];
  float accv = vb2[e];
  const float4* zar = (const float4*)(za + (size_t)b * 512);
  const float4* zvr = (const float4*)(zv + (size_t)b * 512);
  for (int k4 = 0; k4 < 128; ++k4) {
    const float4 z1 = zar[k4];
    const float4 z2 = zvr[k4];
    const float* wvk = &wv[k4 * 4];
    accv = fmaf(z2.x, wvk[0], accv);
    accv = fmaf(z2.y, wvk[1], accv);
    accv = fmaf(z2.z, wvk[2], accv);
    accv = fmaf(z2.w, wvk[3], accv);
    const float* w = &wa[k4 * 4 * 32];
    #pragma unroll
    for (int a = 0; a < 32; ++a) acca[a] = fmaf(z1.x, w[a], acca[a]);
    #pragma unroll
    for (int a = 0; a < 32; ++a) acca[a] = fmaf(z1.y, w[32 + a], acca[a]);
    #pragma unroll
    for (int a = 0; a < 32; ++a) acca[a] = fmaf(z1.z, w[64 + a], acca[a]);
    #pragma unroll
    for (int a = 0; a < 32; ++a) acca[a] = fmaf(z1.w, w[96 + a], acca[a]);
  }
  float mean = 0.f;
  #pragma unroll
  for (int a = 0; a < 32; ++a) mean += acca[a];
  mean *= 0.03125f;
  float* o = out + (size_t)b * 32;
  #pragma unroll
  for (int a = 0; a < 32; ++a) o[a] = acca[a] - mean + accv;
}

extern "C" void kernel_launch(void* const* d_in, const int* in_sizes, int n_in,
                              void* d_out, int out_size, void* d_ws, size_t ws_size,
                              hipStream_t stream) {
  const float* x   = (const float*)d_in[0];
  const float* cW1 = (const float*)d_in[1];
  const float* cb1 = (const float*)d_in[2];
  const float* cW2 = (const float*)d_in[3];
  const float* cb2 = (const float*)d_in[4];
  const float* cW3 = (const float*)d_in[5];
  const float* cb3 = (const float*)d_in[6];
  const float* aW1 = (const float*)d_in[7];
  const float* ab1 = (const float*)d_in[8];
  const float* aW2 = (const float*)d_in[9];
  const float* ab2 = (const float*)d_in[10];
  const float* vW1 = (const float*)d_in[11];
  const float* vb1 = (const float*)d_in[12];
  const float* vW2 = (const float*)d_in[13];
  const float* vb2 = (const float*)d_in[14];
  const float* bd  = (const float*)d_in[15];
  float* out = (float*)d_out;

  char* ws = (char*)d_ws;
  float* h3 = (float*)(ws);                         // 4096*1024*4 = 16,777,216
  float* za = (float*)(ws + 16777216ull);           // 8,388,608 (rows = batch idx)
  float* zv = (float*)(ws + 25165824ull);           // 8,388,608
  int* perm = (int*)(ws + 33554432ull);             // 65,536
  int* cnt  = (int*)(ws + 33619968ull);             // 128 (padded)
  bf16* W1p = (bf16*)(ws + 33620096ull);            // 16,384
  bf16* W2p = (bf16*)(ws + 33636480ull);            // 65,536
  bf16* W3p = (bf16*)(ws + 33702016ull);            // 73,728

  k_cvt_w1<<<32, 256, 0, stream>>>(cW1, W1p);
  k_cvt_w2<<<128, 256, 0, stream>>>(cW2, W2p);
  k_cvt_w3<<<144, 256, 0, stream>>>(cW3, W3p);
  hipMemsetAsync(cnt, 0, 16, stream);
  k_route<<<16, 256, 0, stream>>>(x, bd, perm, cnt);
  k_convs<<<4096, 256, 0, stream>>>(x, W1p, cb1, W2p, cb2, W3p, cb3, h3);
  k_mlp1<<<dim3(64, 8, 8), 256, 0, stream>>>(h3, aW1, ab1, vW1, vb1, perm, cnt, za, zv);
  k_mlp2<<<dim3(16, 4), 256, 0, stream>>>(za, zv, aW2, ab2, vW2, vb2, perm, cnt, out);
}

// Round 5
// 315.613 us; speedup vs baseline: 7.1477x; 1.8765x over previous
//
#include <hip/hip_runtime.h>
#include <hip/hip_bf16.h>

typedef __bf16 bf16;
typedef bf16 bf16x8 __attribute__((ext_vector_type(8)));
typedef bf16 bf16x4 __attribute__((ext_vector_type(4)));
typedef float f32x4 __attribute__((ext_vector_type(4)));

// B=4096, x(4,64,64); conv1 32x4x8x8 s4 ->(32,15,15); conv2 64x32x4x4 s2 ->(64,6,6);
// conv3 64x64x3x3 s1 ->(64,4,4) -> h(1024); routed MLPs E=4: 1024->512->{32,1}; q=(B,32).

// ---- conv weight permute: OIHW f32 -> [oc][ky][kx][ic] bf16 ----
__global__ void k_cvt_w1(const float* __restrict__ w, bf16* __restrict__ o) {
  int i = blockIdx.x * 256 + threadIdx.x;
  if (i >= 32 * 256) return;
  int oc = i >> 8, k = i & 255;
  int ic = k & 3, kp = k >> 2, kx = kp & 7, ky = kp >> 3;
  o[i] = (bf16)w[oc * 256 + ic * 64 + ky * 8 + kx];
}
__global__ void k_cvt_w2(const float* __restrict__ w, bf16* __restrict__ o) {
  int i = blockIdx.x * 256 + threadIdx.x;
  if (i >= 64 * 512) return;
  int oc = i >> 9, k = i & 511;
  int ic = k & 31, kp = k >> 5, kx = kp & 3, ky = kp >> 2;
  o[i] = (bf16)w[oc * 512 + ic * 16 + ky * 4 + kx];
}
__global__ void k_cvt_w3(const float* __restrict__ w, bf16* __restrict__ o) {
  int i = blockIdx.x * 256 + threadIdx.x;
  if (i >= 64 * 576) return;
  int oc = i / 576, k = i - oc * 576;
  int ic = k & 63, kp = k >> 6, kx = kp % 3, ky = kp / 3;
  o[i] = (bf16)w[oc * 576 + ic * 9 + ky * 3 + kx];
}

// ---- MLP L1 weights: [e][k=1024][n=512] f32 -> [(net*4+e)][n=512][k=1024] bf16 ----
__global__ __launch_bounds__(256) void k_cvt_w1T(const float* __restrict__ aW1,
    const float* __restrict__ vW1, bf16* __restrict__ o) {
  __shared__ float t[64][65];
  const int bz = blockIdx.z;            // net*4+e
  const float* in = (bz >= 4 ? vW1 : aW1) + (size_t)(bz & 3) * 524288;
  const int k0 = blockIdx.x * 64, n0 = blockIdx.y * 64;
  const int tid = threadIdx.x, cc = tid & 63, r0 = (tid >> 6) * 16;
  for (int i = 0; i < 16; ++i)
    t[r0 + i][cc] = in[(size_t)(k0 + r0 + i) * 512 + n0 + cc];
  __syncthreads();
  for (int i = 0; i < 16; ++i) {
    int n = r0 + i, k = cc;
    o[((size_t)bz * 512 + n0 + n) * 1024 + k0 + k] = (bf16)t[k][n];
  }
}

// ---- routing ----
__global__ void k_route(const float* __restrict__ x, const float* __restrict__ bd,
                        int* __restrict__ perm, int* __restrict__ inv, int* __restrict__ cnt) {
  const int b = blockIdx.x * 256 + threadIdx.x;
  const float r = x[(size_t)b * 16384 + 12288];   // x[b,3,0,0]
  const int e = (r > bd[0]) + (r > bd[1]) + (r > bd[2]);
  const int pos = atomicAdd(&cnt[e], 1);
  perm[e * 4096 + pos] = b;
  inv[b] = e * 4096 + pos;
}

// ---- fused convs, 1 image/block, weights in registers, bf16 MFMA ----
__global__ __launch_bounds__(256, 3) void k_convs(const float* __restrict__ x,
    const bf16* __restrict__ W1p, const float* __restrict__ b1,
    const bf16* __restrict__ W2p, const float* __restrict__ b2,
    const bf16* __restrict__ W3p, const float* __restrict__ b3,
    const int* __restrict__ inv, bf16* __restrict__ h3s) {
  __shared__ bf16 sA[16384];    // 32 KB: x as [64][64][4]; later reused as h2 [36][64]
  __shared__ bf16 sh1[7200];    // 14.4 KB: h1 [15][15][32]
  const int b = blockIdx.x, tid = threadIdx.x;
  const int lane = tid & 63, wave = tid >> 6;
  const int lid = lane & 15, c = lane >> 4;
  const int invb = inv[b];

  // stage x: pixel-gather, one bf16x4 write per pixel
  {
    const float* xp = x + (size_t)b * 16384;
    for (int p = tid; p < 4096; p += 256) {
      bf16x4 w;
      w[0] = (bf16)xp[p];
      w[1] = (bf16)xp[4096 + p];
      w[2] = (bf16)xp[8192 + p];
      w[3] = (bf16)xp[12288 + p];
      *(bf16x4*)(&sA[p * 4]) = w;
    }
  }
  __syncthreads();

  // conv1: wave -> octile (ot=wave&1), pt strided; B in regs (8 x bf16x8)
  {
    const int ot = wave & 1;
    const int col = ot * 16 + lid;
    const bf16* wb = W1p + col * 256 + c * 8;
    bf16x8 bw[8];
    #pragma unroll
    for (int ks = 0; ks < 8; ++ks) bw[ks] = *(const bf16x8*)(wb + ks * 32);
    const float bias = b1[col];
    for (int pt = (wave >> 1); pt < 15; pt += 2) {
      int p = pt * 16 + lid; if (p > 224) p = 224;
      const int py = p / 15, px = p - py * 15;
      const int abase = py * 1024 + px * 16 + c * 8;
      f32x4 acc = {0.f, 0.f, 0.f, 0.f};
      #pragma unroll
      for (int ks = 0; ks < 8; ++ks)
        acc = __builtin_amdgcn_mfma_f32_16x16x32_bf16(
            *(const bf16x8*)(&sA[abase + ks * 256]), bw[ks], acc, 0, 0, 0);
      #pragma unroll
      for (int r = 0; r < 4; ++r) {
        const int pr = pt * 16 + c * 4 + r;
        if (pr < 225) sh1[pr * 32 + col] = (bf16)fmaxf(acc[r] + bias, 0.f);
      }
    }
  }
  __syncthreads();

  // conv2: wave = octile (4), pt 0..2; B in regs (16 x bf16x8); h2 -> sA (x dead)
  bf16* sh2 = sA;
  {
    const int col = wave * 16 + lid;
    const bf16* wb = W2p + col * 512 + c * 8;
    bf16x8 bw[16];
    #pragma unroll
    for (int ks = 0; ks < 16; ++ks) bw[ks] = *(const bf16x8*)(wb + ks * 32);
    const float bias = b2[col];
    for (int pt = 0; pt < 3; ++pt) {
      int p = pt * 16 + lid; if (p > 35) p = 35;
      const int oy = p / 6, ox = p - oy * 6;
      const int abase = (oy * 30 + ox * 2) * 32 + c * 8;
      f32x4 acc = {0.f, 0.f, 0.f, 0.f};
      #pragma unroll
      for (int ks = 0; ks < 16; ++ks) {
        const int ky = ks >> 2, kx = ks & 3;
        acc = __builtin_amdgcn_mfma_f32_16x16x32_bf16(
            *(const bf16x8*)(&sh1[abase + (ky * 15 + kx) * 32]), bw[ks], acc, 0, 0, 0);
      }
      #pragma unroll
      for (int r = 0; r < 4; ++r) {
        const int pr = pt * 16 + c * 4 + r;
        if (pr < 36) sh2[pr * 64 + col] = (bf16)fmaxf(acc[r] + bias, 0.f);
      }
    }
  }
  __syncthreads();

  // conv3: wave = octile, one ptile; B in regs (18 x bf16x8); write sorted bf16 row
  {
    const int col = wave * 16 + lid;
    const bf16* wb = W3p + col * 576 + c * 8;
    bf16x8 bw[18];
    #pragma unroll
    for (int ks = 0; ks < 18; ++ks) bw[ks] = *(const bf16x8*)(wb + ks * 32);
    const float bias = b3[col];
    const int oy = lid >> 2, ox = lid & 3;
    const int abase = (oy * 6 + ox) * 64 + c * 8;
    f32x4 acc = {0.f, 0.f, 0.f, 0.f};
    #pragma unroll
    for (int ks = 0; ks < 18; ++ks) {
      const int kp = ks >> 1, ky = kp / 3, kx = kp - ky * 3;
      acc = __builtin_amdgcn_mfma_f32_16x16x32_bf16(
          *(const bf16x8*)(&sh2[abase + (ky * 6 + kx) * 64 + (ks & 1) * 32]), bw[ks], acc, 0, 0, 0);
    }
    bf16x4 o;
    #pragma unroll
    for (int r = 0; r < 4; ++r) o[r] = (bf16)fmaxf(acc[r] + bias, 0.f);
    *(bf16x4*)(h3s + (size_t)invb * 1024 + col * 16 + c * 4) = o;
  }
}

// ---- MLP L1: bf16 MFMA GEMM over sorted rows; M=cntE, N=512, K=1024 ----
__global__ __launch_bounds__(256) void k_mlp1(const bf16* __restrict__ h3s,
    const bf16* __restrict__ W1T, const float* __restrict__ ab1, const float* __restrict__ vb1,
    const int* __restrict__ perm, const int* __restrict__ cnt,
    bf16* __restrict__ za, bf16* __restrict__ zv) {
  const int e = blockIdx.z & 3, net = blockIdx.z >> 2;
  const int cntE = cnt[e];
  const int m0 = blockIdx.x * 64;
  if (m0 >= cntE) return;
  const int n0 = blockIdx.y * 64;
  const bf16* Wt = W1T + (size_t)(net * 4 + e) * 524288;
  const float* bb = (net ? vb1 : ab1) + e * 512;
  bf16* z = net ? zv : za;

  __shared__ bf16 As[64 * 72];
  __shared__ int rows[64];
  const int tid = threadIdx.x;
  if (tid < 64) {
    const int j = m0 + tid;
    rows[tid] = perm[e * 4096 + (j < cntE ? j : cntE - 1)];
  }
  const int lane = tid & 63, wave = tid >> 6;
  const int lid = lane & 15, c = lane >> 4;
  const int wm = wave >> 1, wn = wave & 1;
  const int srow = tid >> 2, skoff = (tid & 3) * 16;   // 16-col slice per thread
  const bf16* arow = h3s + ((size_t)e * 4096 + m0 + srow) * 1024 + skoff;
  const int col0 = n0 + wn * 32 + lid;
  const bf16* wcol0 = Wt + (size_t)col0 * 1024 + c * 8;
  const bf16* wcol1 = Wt + (size_t)(col0 + 16) * 1024 + c * 8;
  const int ab0 = (wm * 32 + lid) * 72 + c * 8;
  const int ab1r = (wm * 32 + 16 + lid) * 72 + c * 8;

  f32x4 acc[2][2];
  #pragma unroll
  for (int i = 0; i < 2; ++i)
    #pragma unroll
    for (int j = 0; j < 2; ++j) acc[i][j] = (f32x4){0.f, 0.f, 0.f, 0.f};

  for (int k0 = 0; k0 < 1024; k0 += 64) {
    // stage full 16-col slice: two bf16x8 per thread (fixes half-written tile)
    *(bf16x8*)(&As[srow * 72 + skoff])     = *(const bf16x8*)(arow + k0);
    *(bf16x8*)(&As[srow * 72 + skoff + 8]) = *(const bf16x8*)(arow + k0 + 8);
    __syncthreads();
    bf16x8 b0a = *(const bf16x8*)(wcol0 + k0);
    bf16x8 b0b = *(const bf16x8*)(wcol0 + k0 + 32);
    bf16x8 b1a = *(const bf16x8*)(wcol1 + k0);
    bf16x8 b1b = *(const bf16x8*)(wcol1 + k0 + 32);
    bf16x8 a0a = *(const bf16x8*)(&As[ab0]);
    bf16x8 a0b = *(const bf16x8*)(&As[ab0 + 32]);
    bf16x8 a1a = *(const bf16x8*)(&As[ab1r]);
    bf16x8 a1b = *(const bf16x8*)(&As[ab1r + 32]);
    acc[0][0] = __builtin_amdgcn_mfma_f32_16x16x32_bf16(a0a, b0a, acc[0][0], 0, 0, 0);
    acc[0][1] = __builtin_amdgcn_mfma_f32_16x16x32_bf16(a0a, b1a, acc[0][1], 0, 0, 0);
    acc[1][0] = __builtin_amdgcn_mfma_f32_16x16x32_bf16(a1a, b0a, acc[1][0], 0, 0, 0);
    acc[1][1] = __builtin_amdgcn_mfma_f32_16x16x32_bf16(a1a, b1a, acc[1][1], 0, 0, 0);
    acc[0][0] = __builtin_amdgcn_mfma_f32_16x16x32_bf16(a0b, b0b, acc[0][0], 0, 0, 0);
    acc[0][1] = __builtin_amdgcn_mfma_f32_16x16x32_bf16(a0b, b1b, acc[0][1], 0, 0, 0);
    acc[1][0] = __builtin_amdgcn_mfma_f32_16x16x32_bf16(a1b, b0b, acc[1][0], 0, 0, 0);
    acc[1][1] = __builtin_amdgcn_mfma_f32_16x16x32_bf16(a1b, b1b, acc[1][1], 0, 0, 0);
    __syncthreads();
  }

  #pragma unroll
  for (int nf = 0; nf < 2; ++nf) {
    const int col = col0 + nf * 16;
    const float bias = bb[col];
    #pragma unroll
    for (int mf = 0; mf < 2; ++mf) {
      #pragma unroll
      for (int r = 0; r < 4; ++r) {
        const int ridx = wm * 32 + mf * 16 + c * 4 + r;
        if (m0 + ridx < cntE)
          z[(size_t)rows[ridx] * 512 + col] = (bf16)fmaxf(acc[mf][nf][r] + bias, 0.f);
      }
    }
  }
}

// ---- MLP L2 + dueling combine (bf16 z, f32 weights in LDS) ----
__global__ __launch_bounds__(256) void k_mlp2(const bf16* __restrict__ za,
    const bf16* __restrict__ zv,
    const float* __restrict__ aW2, const float* __restrict__ ab2,
    const float* __restrict__ vW2, const float* __restrict__ vb2,
    const int* __restrict__ perm, const int* __restrict__ cnt,
    float* __restrict__ out) {
  __shared__ float wa[512 * 32];
  __shared__ float wv[512];
  const int e = blockIdx.y;
  const int tid = threadIdx.x;
  {
    const float4* s = (const float4*)(aW2 + (size_t)e * 16384);
    float4* d = (float4*)wa;
    #pragma unroll
    for (int i = 0; i < 16; ++i) d[tid + i * 256] = s[tid + i * 256];
    if (tid < 128) ((float4*)wv)[tid] = ((const float4*)(vW2 + (size_t)e * 512))[tid];
  }
  __syncthreads();
  const int cntE = cnt[e];
  const int j = blockIdx.x * 256 + tid;
  if (j >= cntE) return;
  const int b = perm[e * 4096 + j];

  float acca[32];
  #pragma unroll
  for (int a = 0; a < 32; ++a) acca[a] = ab2[e * 32 + a];
  float accv = vb2[e];
  const bf16* zar = za + (size_t)b * 512;
  const bf16* zvr = zv + (size_t)b * 512;
  for (int kk = 0; kk < 512; kk += 8) {
    bf16x8 z1 = *(const bf16x8*)(zar + kk);
    bf16x8 z2 = *(const bf16x8*)(zvr + kk);
    #pragma unroll
    for (int u = 0; u < 8; ++u) {
      const float zz = (float)z1[u];
      accv = fmaf((float)z2[u], wv[kk + u], accv);
      const float* w = &wa[(kk + u) * 32];
      #pragma unroll
      for (int a = 0; a < 32; ++a) acca[a] = fmaf(zz, w[a], acca[a]);
    }
  }
  float mean = 0.f;
  #pragma unroll
  for (int a = 0; a < 32; ++a) mean += acca[a];
  mean *= 0.03125f;
  float* o = out + (size_t)b * 32;
  #pragma unroll
  for (int a = 0; a < 32; ++a) o[a] = acca[a] - mean + accv;
}

extern "C" void kernel_launch(void* const* d_in, const int* in_sizes, int n_in,
                              void* d_out, int out_size, void* d_ws, size_t ws_size,
                              hipStream_t stream) {
  const float* x   = (const float*)d_in[0];
  const float* cW1 = (const float*)d_in[1];
  const float* cb1 = (const float*)d_in[2];
  const float* cW2 = (const float*)d_in[3];
  const float* cb2 = (const float*)d_in[4];
  const float* cW3 = (const float*)d_in[5];
  const float* cb3 = (const float*)d_in[6];
  const float* aW1 = (const float*)d_in[7];
  const float* ab1 = (const float*)d_in[8];
  const float* aW2 = (const float*)d_in[9];
  const float* ab2 = (const float*)d_in[10];
  const float* vW1 = (const float*)d_in[11];
  const float* vb1 = (const float*)d_in[12];
  const float* vW2 = (const float*)d_in[13];
  const float* vb2 = (const float*)d_in[14];
  const float* bd  = (const float*)d_in[15];
  float* out = (float*)d_out;

  char* ws = (char*)d_ws;
  bf16* h3s = (bf16*)(ws);                          // 16384 x 1024 bf16 = 33,554,432
  bf16* za  = (bf16*)(ws + 33554432ull);            // 4096 x 512 bf16 = 4,194,304
  bf16* zv  = (bf16*)(ws + 37748736ull);            // 4,194,304
  bf16* W1T = (bf16*)(ws + 41943040ull);            // 8 x 512 x 1024 bf16 = 8,388,608
  bf16* W1p = (bf16*)(ws + 50331648ull);            // 16,384
  bf16* W2p = (bf16*)(ws + 50348032ull);            // 65,536
  bf16* W3p = (bf16*)(ws + 50413568ull);            // 73,728
  int* perm = (int*)(ws + 50487296ull);             // 65,536
  int* inv  = (int*)(ws + 50552832ull);             // 16,384
  int* cnt  = (int*)(ws + 50569216ull);             // 64

  k_cvt_w1<<<32, 256, 0, stream>>>(cW1, W1p);
  k_cvt_w2<<<128, 256, 0, stream>>>(cW2, W2p);
  k_cvt_w3<<<144, 256, 0, stream>>>(cW3, W3p);
  k_cvt_w1T<<<dim3(16, 8, 8), 256, 0, stream>>>(aW1, vW1, W1T);
  hipMemsetAsync(cnt, 0, 16, stream);
  k_route<<<16, 256, 0, stream>>>(x, bd, perm, inv, cnt);
  k_convs<<<4096, 256, 0, stream>>>(x, W1p, cb1, W2p, cb2, W3p, cb3, inv, h3s);
  k_mlp1<<<dim3(64, 8, 8), 256, 0, stream>>>(h3s, W1T, ab1, vb1, perm, cnt, za, zv);
  k_mlp2<<<dim3(16, 4), 256, 0, stream>>>(za, zv, aW2, ab2, vW2, vb2, perm, cnt, out);
}

// Round 6
// 289.221 us; speedup vs baseline: 7.8000x; 1.0913x over previous
//
#include <hip/hip_runtime.h>
#include <hip/hip_bf16.h>

typedef __bf16 bf16;
typedef bf16 bf16x8 __attribute__((ext_vector_type(8)));
typedef bf16 bf16x4 __attribute__((ext_vector_type(4)));
typedef float f32x4 __attribute__((ext_vector_type(4)));

// B=4096, x(4,64,64); conv1 32x4x8x8 s4 ->(32,15,15); conv2 64x32x4x4 s2 ->(64,6,6);
// conv3 64x64x3x3 s1 ->(64,4,4) -> h(1024); routed MLPs E=4: 1024->512->{32,1}; q=(B,32).

// ---- conv weight permute: OIHW f32 -> [oc][ky][kx][ic] bf16 ----
__global__ void k_cvt_w1(const float* __restrict__ w, bf16* __restrict__ o) {
  int i = blockIdx.x * 256 + threadIdx.x;
  if (i >= 32 * 256) return;
  int oc = i >> 8, k = i & 255;
  int ic = k & 3, kp = k >> 2, kx = kp & 7, ky = kp >> 3;
  o[i] = (bf16)w[oc * 256 + ic * 64 + ky * 8 + kx];
}
__global__ void k_cvt_w2(const float* __restrict__ w, bf16* __restrict__ o) {
  int i = blockIdx.x * 256 + threadIdx.x;
  if (i >= 64 * 512) return;
  int oc = i >> 9, k = i & 511;
  int ic = k & 31, kp = k >> 5, kx = kp & 3, ky = kp >> 2;
  o[i] = (bf16)w[oc * 512 + ic * 16 + ky * 4 + kx];
}
__global__ void k_cvt_w3(const float* __restrict__ w, bf16* __restrict__ o) {
  int i = blockIdx.x * 256 + threadIdx.x;
  if (i >= 64 * 576) return;
  int oc = i / 576, k = i - oc * 576;
  int ic = k & 63, kp = k >> 6, kx = kp % 3, ky = kp / 3;
  o[i] = (bf16)w[oc * 576 + ic * 9 + ky * 3 + kx];
}

// ---- MLP L1 weights: [e][k=1024][n=512] f32 -> [(net*4+e)][n=512][k=1024] bf16 ----
__global__ __launch_bounds__(256) void k_cvt_w1T(const float* __restrict__ aW1,
    const float* __restrict__ vW1, bf16* __restrict__ o) {
  __shared__ float t[64][65];
  const int bz = blockIdx.z;            // net*4+e
  const float* in = (bz >= 4 ? vW1 : aW1) + (size_t)(bz & 3) * 524288;
  const int k0 = blockIdx.x * 64, n0 = blockIdx.y * 64;
  const int tid = threadIdx.x, cc = tid & 63, r0 = (tid >> 6) * 16;
  for (int i = 0; i < 16; ++i)
    t[r0 + i][cc] = in[(size_t)(k0 + r0 + i) * 512 + n0 + cc];
  __syncthreads();
  for (int i = 0; i < 16; ++i) {
    int n = r0 + i, k = cc;
    o[((size_t)bz * 512 + n0 + n) * 1024 + k0 + k] = (bf16)t[k][n];
  }
}

// ---- routing ----
__global__ void k_route(const float* __restrict__ x, const float* __restrict__ bd,
                        int* __restrict__ perm, int* __restrict__ cnt) {
  const int b = blockIdx.x * 256 + threadIdx.x;
  const float r = x[(size_t)b * 16384 + 12288];   // x[b,3,0,0]
  const int e = (r > bd[0]) + (r > bd[1]) + (r > bd[2]);
  const int pos = atomicAdd(&cnt[e], 1);
  perm[e * 4096 + pos] = b;
}

// ---- fused convs, 1 image/block, ks-chunked weights, bf16 MFMA ----
__global__ __launch_bounds__(256, 3) void k_convs(const float* __restrict__ x,
    const bf16* __restrict__ W1p, const float* __restrict__ b1,
    const bf16* __restrict__ W2p, const float* __restrict__ b2,
    const bf16* __restrict__ W3p, const float* __restrict__ b3,
    bf16* __restrict__ h3) {
  __shared__ bf16 sA[16384];    // 32 KB: x as [64][64][4]; reused as h2 [36][64]
  __shared__ bf16 sh1[7200];    // 14.4 KB: h1 [15][15][32]
  const int b = blockIdx.x, tid = threadIdx.x;
  const int lane = tid & 63, wave = tid >> 6;
  const int lid = lane & 15, c = lane >> 4;

  // stage x: 4 pixels/thread/iter via 4x float4, one 32B LDS write
  {
    const float4* xs = (const float4*)(x + (size_t)b * 16384);
    for (int g = tid; g < 1024; g += 256) {
      float4 v0 = xs[g], v1 = xs[1024 + g], v2 = xs[2048 + g], v3 = xs[3072 + g];
      bf16x8 lo, hi;
      lo[0] = (bf16)v0.x; lo[1] = (bf16)v1.x; lo[2] = (bf16)v2.x; lo[3] = (bf16)v3.x;
      lo[4] = (bf16)v0.y; lo[5] = (bf16)v1.y; lo[6] = (bf16)v2.y; lo[7] = (bf16)v3.y;
      hi[0] = (bf16)v0.z; hi[1] = (bf16)v1.z; hi[2] = (bf16)v2.z; hi[3] = (bf16)v3.z;
      hi[4] = (bf16)v0.w; hi[5] = (bf16)v1.w; hi[6] = (bf16)v2.w; hi[7] = (bf16)v3.w;
      *(bf16x8*)(&sA[g * 16]) = lo;
      *(bf16x8*)(&sA[g * 16 + 8]) = hi;
    }
  }
  __syncthreads();

  // conv1: wave -> octile (wave&1), 8 pt slots; K chunked 2x4
  {
    const int col = (wave & 1) * 16 + lid;
    const bf16* wb = W1p + col * 256 + c * 8;
    const float bias = b1[col];
    const int pt0 = wave >> 1;
    int ab[8];
    #pragma unroll
    for (int pi = 0; pi < 8; ++pi) {
      int pt = pt0 + 2 * pi; if (pt > 14) pt = 14;
      int p = pt * 16 + lid; if (p > 224) p = 224;
      const int py = p / 15, px = p - py * 15;
      ab[pi] = py * 1024 + px * 16 + c * 8;
    }
    f32x4 acc[8];
    #pragma unroll
    for (int pi = 0; pi < 8; ++pi) acc[pi] = (f32x4){0.f, 0.f, 0.f, 0.f};
    #pragma unroll
    for (int ksc = 0; ksc < 2; ++ksc) {
      bf16x8 bw[4];
      #pragma unroll
      for (int j = 0; j < 4; ++j) bw[j] = *(const bf16x8*)(wb + (ksc * 4 + j) * 32);
      #pragma unroll
      for (int pi = 0; pi < 8; ++pi)
        #pragma unroll
        for (int j = 0; j < 4; ++j)
          acc[pi] = __builtin_amdgcn_mfma_f32_16x16x32_bf16(
              *(const bf16x8*)(&sA[ab[pi] + (ksc * 4 + j) * 256]), bw[j], acc[pi], 0, 0, 0);
    }
    #pragma unroll
    for (int pi = 0; pi < 8; ++pi) {
      int pt = pt0 + 2 * pi; if (pt > 14) pt = 14;
      #pragma unroll
      for (int r = 0; r < 4; ++r) {
        const int pr = pt * 16 + c * 4 + r;
        if (pr < 225) sh1[pr * 32 + col] = (bf16)fmaxf(acc[pi][r] + bias, 0.f);
      }
    }
  }
  __syncthreads();

  // conv2: wave = octile, 3 pt; K chunked 4x4; h2 -> sA (x dead)
  bf16* sh2 = sA;
  {
    const int col = wave * 16 + lid;
    const bf16* wb = W2p + col * 512 + c * 8;
    const float bias = b2[col];
    int ab2[3];
    #pragma unroll
    for (int pt = 0; pt < 3; ++pt) {
      int p = pt * 16 + lid; if (p > 35) p = 35;
      const int oy = p / 6, ox = p - oy * 6;
      ab2[pt] = (oy * 30 + ox * 2) * 32 + c * 8;
    }
    f32x4 acc[3];
    #pragma unroll
    for (int pt = 0; pt < 3; ++pt) acc[pt] = (f32x4){0.f, 0.f, 0.f, 0.f};
    #pragma unroll
    for (int ksc = 0; ksc < 4; ++ksc) {
      bf16x8 bw[4];
      #pragma unroll
      for (int j = 0; j < 4; ++j) bw[j] = *(const bf16x8*)(wb + (ksc * 4 + j) * 32);
      #pragma unroll
      for (int pt = 0; pt < 3; ++pt)
        #pragma unroll
        for (int j = 0; j < 4; ++j) {
          const int ks = ksc * 4 + j, ky = ks >> 2, kx = ks & 3;
          acc[pt] = __builtin_amdgcn_mfma_f32_16x16x32_bf16(
              *(const bf16x8*)(&sh1[ab2[pt] + (ky * 15 + kx) * 32]), bw[j], acc[pt], 0, 0, 0);
        }
    }
    __syncthreads();   // before overwriting sA rows? sh1 is separate; sA write below is h2 — must wait for conv2 reads of sh1 only. sA was last read in conv1; all waves passed that barrier.
    #pragma unroll
    for (int pt = 0; pt < 3; ++pt)
      #pragma unroll
      for (int r = 0; r < 4; ++r) {
        const int pr = pt * 16 + c * 4 + r;
        if (pr < 36) sh2[pr * 64 + col] = (bf16)fmaxf(acc[pt][r] + bias, 0.f);
      }
  }
  __syncthreads();

  // conv3: wave = octile, 1 pt; K chunked 3x6; write h3[b] (b-indexed)
  {
    const int col = wave * 16 + lid;
    const bf16* wb = W3p + col * 576 + c * 8;
    const float bias = b3[col];
    const int oy = lid >> 2, ox = lid & 3;
    const int ab3 = (oy * 6 + ox) * 64 + c * 8;
    f32x4 acc = {0.f, 0.f, 0.f, 0.f};
    #pragma unroll
    for (int ksc = 0; ksc < 3; ++ksc) {
      bf16x8 bw[6];
      #pragma unroll
      for (int j = 0; j < 6; ++j) bw[j] = *(const bf16x8*)(wb + (ksc * 6 + j) * 32);
      #pragma unroll
      for (int j = 0; j < 6; ++j) {
        const int ks = ksc * 6 + j, kp = ks >> 1, ky = kp / 3, kx = kp - ky * 3;
        acc = __builtin_amdgcn_mfma_f32_16x16x32_bf16(
            *(const bf16x8*)(&sh2[ab3 + (ky * 6 + kx) * 64 + (ks & 1) * 32]), bw[j], acc, 0, 0, 0);
      }
    }
    bf16x4 o;
    #pragma unroll
    for (int r = 0; r < 4; ++r) o[r] = (bf16)fmaxf(acc[r] + bias, 0.f);
    *(bf16x4*)(h3 + (size_t)b * 1024 + col * 16 + c * 4) = o;
  }
}

// ---- MLP L1: fused nets, tile M=64 x N=128, bf16 MFMA; h3 gathered via perm ----
__global__ __launch_bounds__(256, 2) void k_mlp1(const bf16* __restrict__ h3,
    const bf16* __restrict__ W1T, const float* __restrict__ ab1, const float* __restrict__ vb1,
    const int* __restrict__ perm, const int* __restrict__ cnt,
    bf16* __restrict__ za, bf16* __restrict__ zv) {
  const int e = blockIdx.z;
  const int cntE = cnt[e];
  const int m0 = blockIdx.x * 64;
  if (m0 >= cntE) return;
  const int n0 = blockIdx.y * 128;
  const bf16* WA = W1T + (size_t)e * 524288;
  const bf16* WV = W1T + (size_t)(4 + e) * 524288;

  __shared__ bf16 As[64 * 72];
  __shared__ int rows[64];
  const int tid = threadIdx.x;
  if (tid < 64) {
    int j = m0 + tid; if (j > cntE - 1) j = cntE - 1;
    rows[tid] = perm[e * 4096 + j];
  }
  __syncthreads();

  const int lane = tid & 63, wave = tid >> 6;
  const int lid = lane & 15, c = lane >> 4;
  const int wm = wave >> 1, wn = wave & 1;
  const int srow = tid >> 2, skoff = (tid & 3) * 16;
  const bf16* arow = h3 + (size_t)rows[srow] * 1024 + skoff;
  const int cb = n0 + wn * 64 + lid;
  const bf16* pA[4];
  const bf16* pV[4];
  #pragma unroll
  for (int cf = 0; cf < 4; ++cf) {
    pA[cf] = WA + (size_t)(cb + cf * 16) * 1024 + c * 8;
    pV[cf] = WV + (size_t)(cb + cf * 16) * 1024 + c * 8;
  }
  const int abm[2] = {(wm * 32 + lid) * 72 + c * 8, (wm * 32 + 16 + lid) * 72 + c * 8};

  f32x4 acc[2][2][4];   // [net][mf][cf]
  #pragma unroll
  for (int n = 0; n < 2; ++n)
    #pragma unroll
    for (int m = 0; m < 2; ++m)
      #pragma unroll
      for (int f = 0; f < 4; ++f) acc[n][m][f] = (f32x4){0.f, 0.f, 0.f, 0.f};

  for (int k0 = 0; k0 < 1024; k0 += 64) {
    *(bf16x8*)(&As[srow * 72 + skoff])     = *(const bf16x8*)(arow + k0);
    *(bf16x8*)(&As[srow * 72 + skoff + 8]) = *(const bf16x8*)(arow + k0 + 8);
    __syncthreads();
    bf16x8 a[2][2];
    #pragma unroll
    for (int m = 0; m < 2; ++m)
      #pragma unroll
      for (int ks = 0; ks < 2; ++ks) a[m][ks] = *(const bf16x8*)(&As[abm[m] + ks * 32]);
    #pragma unroll
    for (int cf = 0; cf < 4; ++cf)
      #pragma unroll
      for (int ks = 0; ks < 2; ++ks) {
        bf16x8 bA = *(const bf16x8*)(pA[cf] + k0 + ks * 32);
        bf16x8 bV = *(const bf16x8*)(pV[cf] + k0 + ks * 32);
        #pragma unroll
        for (int m = 0; m < 2; ++m) {
          acc[0][m][cf] = __builtin_amdgcn_mfma_f32_16x16x32_bf16(a[m][ks], bA, acc[0][m][cf], 0, 0, 0);
          acc[1][m][cf] = __builtin_amdgcn_mfma_f32_16x16x32_bf16(a[m][ks], bV, acc[1][m][cf], 0, 0, 0);
        }
      }
    __syncthreads();
  }

  #pragma unroll
  for (int cf = 0; cf < 4; ++cf) {
    const int colc = cb + cf * 16;
    const float bA = ab1[e * 512 + colc];
    const float bV = vb1[e * 512 + colc];
    #pragma unroll
    for (int m = 0; m < 2; ++m)
      #pragma unroll
      for (int r = 0; r < 4; ++r) {
        const int ridx = wm * 32 + m * 16 + c * 4 + r;
        if (m0 + ridx < cntE) {
          const size_t zoff = (size_t)rows[ridx] * 512 + colc;
          za[zoff] = (bf16)fmaxf(acc[0][m][cf][r] + bA, 0.f);
          zv[zoff] = (bf16)fmaxf(acc[1][m][cf][r] + bV, 0.f);
        }
      }
  }
}

// ---- MLP L2 + dueling combine via MFMA (B = [wa | wv | 0] in LDS) ----
__global__ __launch_bounds__(256) void k_mlp2(const bf16* __restrict__ za,
    const bf16* __restrict__ zv,
    const float* __restrict__ aW2, const float* __restrict__ ab2,
    const float* __restrict__ vW2, const float* __restrict__ vb2,
    const int* __restrict__ perm, const int* __restrict__ cnt,
    float* __restrict__ out) {
  const int e = blockIdx.y;
  const int cntE = cnt[e];
  const int m0 = blockIdx.x * 64;
  if (m0 >= cntE) return;
  __shared__ bf16 Bs[48 * 520];   // [n][k], pad 520 kills bank conflicts
  const int tid = threadIdx.x;
  for (int i = tid; i < 512 * 32; i += 256) {
    const int k = i >> 5, n = i & 31;
    Bs[n * 520 + k] = (bf16)aW2[(size_t)e * 16384 + i];
  }
  for (int i = tid; i < 512; i += 256) Bs[32 * 520 + i] = (bf16)vW2[e * 512 + i];
  for (int i = tid; i < 15 * 512; i += 256) {
    const int n = 33 + (i >> 9), k = i & 511;
    Bs[n * 520 + k] = (bf16)0.f;
  }
  __syncthreads();

  const int lane = tid & 63, wave = tid >> 6;
  const int lid = lane & 15, c = lane >> 4;
  const int row0 = m0 + wave * 16;
  if (row0 >= cntE) return;
  int rowl = row0 + lid; if (rowl > cntE - 1) rowl = cntE - 1;
  const int pb = perm[e * 4096 + rowl];
  const bf16* aA = za + (size_t)pb * 512 + c * 8;
  const bf16* aV = zv + (size_t)pb * 512 + c * 8;

  f32x4 acc0 = {0.f, 0.f, 0.f, 0.f}, acc1 = acc0, accv = acc0;
  #pragma unroll
  for (int k0 = 0; k0 < 512; k0 += 32) {
    bf16x8 a1 = *(const bf16x8*)(aA + k0);
    bf16x8 a2 = *(const bf16x8*)(aV + k0);
    bf16x8 b0 = *(const bf16x8*)(&Bs[lid * 520 + k0 + c * 8]);
    bf16x8 b1 = *(const bf16x8*)(&Bs[(16 + lid) * 520 + k0 + c * 8]);
    bf16x8 b2 = *(const bf16x8*)(&Bs[(32 + lid) * 520 + k0 + c * 8]);
    acc0 = __builtin_amdgcn_mfma_f32_16x16x32_bf16(a1, b0, acc0, 0, 0, 0);
    acc1 = __builtin_amdgcn_mfma_f32_16x16x32_bf16(a1, b1, acc1, 0, 0, 0);
    accv = __builtin_amdgcn_mfma_f32_16x16x32_bf16(a2, b2, accv, 0, 0, 0);
  }

  const float ba0 = ab2[e * 32 + lid], ba1 = ab2[e * 32 + 16 + lid], bv = vb2[e];
  #pragma unroll
  for (int r = 0; r < 4; ++r) {
    const int row = row0 + c * 4 + r;
    const float y0 = acc0[r] + ba0, y1 = acc1[r] + ba1;
    float s = y0 + y1;
    s += __shfl_xor(s, 1); s += __shfl_xor(s, 2);
    s += __shfl_xor(s, 4); s += __shfl_xor(s, 8);
    const float mean = s * 0.03125f;
    const float ys = __shfl(accv[r], lane & 48) + bv;
    if (row < cntE) {
      const int bq = perm[e * 4096 + row];
      out[(size_t)bq * 32 + lid] = y0 - mean + ys;
      out[(size_t)bq * 32 + 16 + lid] = y1 - mean + ys;
    }
  }
}

extern "C" void kernel_launch(void* const* d_in, const int* in_sizes, int n_in,
                              void* d_out, int out_size, void* d_ws, size_t ws_size,
                              hipStream_t stream) {
  const float* x   = (const float*)d_in[0];
  const float* cW1 = (const float*)d_in[1];
  const float* cb1 = (const float*)d_in[2];
  const float* cW2 = (const float*)d_in[3];
  const float* cb2 = (const float*)d_in[4];
  const float* cW3 = (const float*)d_in[5];
  const float* cb3 = (const float*)d_in[6];
  const float* aW1 = (const float*)d_in[7];
  const float* ab1 = (const float*)d_in[8];
  const float* aW2 = (const float*)d_in[9];
  const float* ab2 = (const float*)d_in[10];
  const float* vW1 = (const float*)d_in[11];
  const float* vb1 = (const float*)d_in[12];
  const float* vW2 = (const float*)d_in[13];
  const float* vb2 = (const float*)d_in[14];
  const float* bd  = (const float*)d_in[15];
  float* out = (float*)d_out;

  char* ws = (char*)d_ws;
  bf16* h3  = (bf16*)(ws);                          // 4096*1024*2 = 8,388,608
  bf16* za  = (bf16*)(ws + 8388608ull);             // 4,194,304
  bf16* zv  = (bf16*)(ws + 12582912ull);            // 4,194,304
  bf16* W1T = (bf16*)(ws + 16777216ull);            // 8,388,608
  bf16* W1p = (bf16*)(ws + 25165824ull);            // 16,384
  bf16* W2p = (bf16*)(ws + 25182208ull);            // 65,536
  bf16* W3p = (bf16*)(ws + 25247744ull);            // 73,728
  int* perm = (int*)(ws + 25321472ull);             // 65,536
  int* cnt  = (int*)(ws + 25387008ull);             // 64

  k_cvt_w1<<<32, 256, 0, stream>>>(cW1, W1p);
  k_cvt_w2<<<128, 256, 0, stream>>>(cW2, W2p);
  k_cvt_w3<<<144, 256, 0, stream>>>(cW3, W3p);
  k_cvt_w1T<<<dim3(16, 8, 8), 256, 0, stream>>>(aW1, vW1, W1T);
  hipMemsetAsync(cnt, 0, 16, stream);
  k_route<<<16, 256, 0, stream>>>(x, bd, perm, cnt);
  k_convs<<<4096, 256, 0, stream>>>(x, W1p, cb1, W2p, cb2, W3p, cb3, h3);
  k_mlp1<<<dim3(64, 4, 4), 256, 0, stream>>>(h3, W1T, ab1, vb1, perm, cnt, za, zv);
  k_mlp2<<<dim3(64, 4), 256, 0, stream>>>(za, zv, aW2, ab2, vW2, vb2, perm, cnt, out);
}